// Round 1
// baseline (1249.473 us; speedup 1.0000x reference)
//
#include <hip/hip_runtime.h>
#include <hip/hip_bf16.h>
#include <cstdint>
#include <cstddef>

// Problem dims (fixed by the reference)
#define B_ROWS 2048
#define L_DIM  2048
#define NBR    16
#define H_DIM  1024
#define M_DIM  (B_ROWS * NBR)   // 32768
#define SLOPE_C 0.01f

#define BM 128
#define BN 128
#define BK 64

typedef unsigned short u16;
typedef __attribute__((ext_vector_type(4))) float f32x4;
typedef __attribute__((ext_vector_type(4))) short s16x4;
typedef __attribute__((ext_vector_type(8))) __bf16 bfrag8;   // MFMA operand (4 VGPRs)

// ---------------------------------------------------------------------------
// Kernel 1: row-wise quicknorm of concat(src, tgt) -> xn (fp32)
// ---------------------------------------------------------------------------
__global__ __launch_bounds__(256) void norm_kernel(const float* __restrict__ src,
                                                   const float* __restrict__ tgt,
                                                   float* __restrict__ xn) {
  const int b = blockIdx.x;
  const int t = threadIdx.x;
  const float* srow = src + (size_t)b * (L_DIM - 4);
  const float* trow = tgt + (size_t)b * 4;
  float v[8];
  float s = 0.f, ss = 0.f;
#pragma unroll
  for (int i = 0; i < 8; ++i) {
    const int idx = t + i * 256;
    const float x = (idx < L_DIM - 4) ? srow[idx] : trow[idx - (L_DIM - 4)];
    v[i] = x;
    s += x;
    ss += x * x;
  }
#pragma unroll
  for (int o = 32; o > 0; o >>= 1) {
    s  += __shfl_xor(s, o, 64);
    ss += __shfl_xor(ss, o, 64);
  }
  __shared__ float red[2][4];
  const int lane = t & 63, wv = t >> 6;
  if (lane == 0) { red[0][wv] = s; red[1][wv] = ss; }
  __syncthreads();
  s  = red[0][0] + red[0][1] + red[0][2] + red[0][3];
  ss = red[1][0] + red[1][1] + red[1][2] + red[1][3];
  const float mu  = s * (1.f / L_DIM);
  const float var = (ss - (float)L_DIM * mu * mu) * (1.f / (L_DIM - 1));
  const float inv = 1.f / sqrtf(var);   // quicknorm: (x-mu)/sd, ddof=1
  float* xrow = xn + (size_t)b * L_DIM;
#pragma unroll
  for (int i = 0; i < 8; ++i) {
    const int idx = t + i * 256;
    xrow[idx] = (v[i] - mu) * inv;
  }
}

// ---------------------------------------------------------------------------
// Kernel 2: 16 reflect-padded conv branches -> z (fp32) stored in d_out
// z[b,k,l] = conv_b[k] + sum_j conv_w[k,j] * xn[b, R(l + j - k/2)]
// ---------------------------------------------------------------------------
__global__ __launch_bounds__(256) void conv_kernel(const float* __restrict__ xn,
                                                   const float* __restrict__ conv_w,
                                                   const float* __restrict__ conv_b,
                                                   float* __restrict__ z) {
  __shared__ float win[272];
  __shared__ float cw[16][16];
  __shared__ float cb[16];
  const int b  = blockIdx.y;
  const int l0 = blockIdx.x * 256;
  const int t  = threadIdx.x;
  cw[t >> 4][t & 15] = conv_w[t];
  if (t < 16) cb[t] = conv_b[t];
  const float* xrow = xn + (size_t)b * L_DIM;
  for (int i = t; i < 271; i += 256) {
    int g = l0 - 7 + i;            // global position, range [-7, L+14]
    int r = g < 0 ? -g : g;        // jnp.pad 'reflect' (edge not repeated)
    if (r >= L_DIM) r = 2 * L_DIM - 2 - r;
    win[i] = xrow[r];
  }
  __syncthreads();
  const int l = l0 + t;
  float* zb = z + (size_t)b * NBR * L_DIM + l;
#pragma unroll
  for (int k = 0; k < NBR; ++k) {
    const int left = k >> 1;
    float a = cb[k];
    const int base = t + 7 - left;
#pragma unroll
    for (int j = 0; j <= k; ++j) a += cw[k][j] * win[base + j];
    zb[(size_t)k * L_DIM] = a;
  }
}

// ---------------------------------------------------------------------------
// Kernel 3: split fp32 -> (hi, lo) truncated bf16 pair.  f ~= hi + lo with
// relative error ~2^-16 (trunc hi keeps top 8 mantissa bits; residual is
// exact, trunc again for lo).
// ---------------------------------------------------------------------------
__global__ __launch_bounds__(256) void split_kernel(const float* __restrict__ src,
                                                    u16* __restrict__ hi,
                                                    u16* __restrict__ lo, int n) {
  const int i = blockIdx.x * 256 + threadIdx.x;
  if (i >= n) return;
  const float f = src[i];
  const unsigned u = __float_as_uint(f);
  const u16 h = (u16)(u >> 16);
  const float r = f - __uint_as_float(u & 0xFFFF0000u);  // exact
  hi[i] = h;
  lo[i] = (u16)(__float_as_uint(r) >> 16);
}

// ---------------------------------------------------------------------------
// GEMM1: H = lrelu(Z @ W1^T + b1).  Z fp32 [32768][2048] (in d_out),
// W1 pre-split hi/lo bf16 [1024][2048].  Output H as hi/lo bf16 [32768][1024].
// 3-term split product: Ahi*Bhi + Ahi*Blo + Alo*Bhi.
// ---------------------------------------------------------------------------
__global__ __launch_bounds__(256, 2) void gemm1_kernel(
    const float* __restrict__ Z,
    const u16* __restrict__ Bhi_g, const u16* __restrict__ Blo_g,
    const float* __restrict__ bias,
    u16* __restrict__ Hhi, u16* __restrict__ Hlo) {
  __shared__ u16 As[2][BM][BK];   // [hi/lo][row][k]  2*16KB
  __shared__ u16 Bs[2][BM][BK];   // 2*16KB
  const int nwg = gridDim.x;
  const int bid = ((int)blockIdx.x % 8) * (nwg / 8) + (int)blockIdx.x / 8;  // XCD chunk
  const int t = threadIdx.x;
  const int lane = t & 63, wv = t >> 6;
  const int wr = wv >> 1, wc = wv & 1;
  const int tn = bid & 7;                       // 1024/128 = 8 N tiles
  const size_t m0 = (size_t)(bid >> 3) * BM;
  const int n0 = tn * BN;
  f32x4 acc[4][4] = {};
  const int a_c4 = (t & 15) * 4;
  const int a_r0 = t >> 4;
  const int fr = lane & 15;
  const int kq = (lane >> 4) * 8;

  for (int k0 = 0; k0 < L_DIM; k0 += BK) {
    // --- stage A: fp32 -> hi/lo bf16 in LDS (reg-staged, truncation split)
#pragma unroll
    for (int i = 0; i < 8; ++i) {
      const int row = a_r0 + i * 16;
      const f32x4 v = *(const f32x4*)(Z + (m0 + row) * (size_t)L_DIM + k0 + a_c4);
      s16x4 hi4, lo4;
#pragma unroll
      for (int e = 0; e < 4; ++e) {
        const unsigned u = __float_as_uint(v[e]);
        hi4[e] = (short)(u >> 16);
        const float r = v[e] - __uint_as_float(u & 0xFFFF0000u);
        lo4[e] = (short)(__float_as_uint(r) >> 16);
      }
      *(s16x4*)&As[0][row][a_c4] = hi4;
      *(s16x4*)&As[1][row][a_c4] = lo4;
    }
    // --- stage B: async global->LDS, width 16 (linear dest, per-lane src)
#pragma unroll
    for (int it = 0; it < 4; ++it) {
      const int idx = (it * 4 + wv) * 64 + lane;
      const int row = idx >> 3;
      const int c8 = (idx & 7) * 8;
      const size_t goff = (size_t)(n0 + row) * L_DIM + k0 + c8;
      __builtin_amdgcn_global_load_lds(
          (const __attribute__((address_space(1))) void*)(Bhi_g + goff),
          (__attribute__((address_space(3))) void*)&Bs[0][row][c8], 16, 0, 0);
      __builtin_amdgcn_global_load_lds(
          (const __attribute__((address_space(1))) void*)(Blo_g + goff),
          (__attribute__((address_space(3))) void*)&Bs[1][row][c8], 16, 0, 0);
    }
    __syncthreads();
    // --- MFMA: 2 k-substeps x 4x4 fragments x 3 split terms
#pragma unroll
    for (int kk = 0; kk < 2; ++kk) {
      bfrag8 ah[4], al[4], bh[4], bl[4];
      const int kb = kk * 32 + kq;
#pragma unroll
      for (int mr = 0; mr < 4; ++mr) {
        ah[mr] = *(const bfrag8*)&As[0][wr * 64 + mr * 16 + fr][kb];
        al[mr] = *(const bfrag8*)&As[1][wr * 64 + mr * 16 + fr][kb];
      }
#pragma unroll
      for (int nr = 0; nr < 4; ++nr) {
        bh[nr] = *(const bfrag8*)&Bs[0][wc * 64 + nr * 16 + fr][kb];
        bl[nr] = *(const bfrag8*)&Bs[1][wc * 64 + nr * 16 + fr][kb];
      }
#pragma unroll
      for (int mr = 0; mr < 4; ++mr)
#pragma unroll
        for (int nr = 0; nr < 4; ++nr) {
          acc[mr][nr] = __builtin_amdgcn_mfma_f32_16x16x32_bf16(ah[mr], bh[nr], acc[mr][nr], 0, 0, 0);
          acc[mr][nr] = __builtin_amdgcn_mfma_f32_16x16x32_bf16(ah[mr], bl[nr], acc[mr][nr], 0, 0, 0);
          acc[mr][nr] = __builtin_amdgcn_mfma_f32_16x16x32_bf16(al[mr], bh[nr], acc[mr][nr], 0, 0, 0);
        }
    }
    __syncthreads();
  }
  // --- epilogue: bias + leaky_relu, write h as hi/lo bf16
  const int rq = (lane >> 4) * 4;
#pragma unroll
  for (int nr = 0; nr < 4; ++nr) {
    const int col = n0 + wc * 64 + nr * 16 + fr;
    const float bv = bias[col];
#pragma unroll
    for (int mr = 0; mr < 4; ++mr) {
#pragma unroll
      for (int j = 0; j < 4; ++j) {
        const size_t row = m0 + wr * 64 + mr * 16 + rq + j;   // C/D: col=lane&15, row=(lane>>4)*4+j
        float vv = acc[mr][nr][j] + bv;
        vv = vv >= 0.f ? vv : SLOPE_C * vv;
        const unsigned u = __float_as_uint(vv);
        const float r = vv - __uint_as_float(u & 0xFFFF0000u);
        Hhi[row * H_DIM + col] = (u16)(u >> 16);
        Hlo[row * H_DIM + col] = (u16)(__float_as_uint(r) >> 16);
      }
    }
  }
}

// ---------------------------------------------------------------------------
// GEMM2: out = z + lrelu(H @ W2^T + b2).  H hi/lo bf16 [32768][1024],
// W2 hi/lo bf16 [2048][1024].  z fp32 lives in d_out; in-place finalize.
// ---------------------------------------------------------------------------
__global__ __launch_bounds__(256, 2) void gemm2_kernel(
    const u16* __restrict__ Ahi_g, const u16* __restrict__ Alo_g,
    const u16* __restrict__ Bhi_g, const u16* __restrict__ Blo_g,
    const float* __restrict__ bias,
    float* __restrict__ OutZ) {
  __shared__ u16 As[2][BM][BK];
  __shared__ u16 Bs[2][BM][BK];
  const int nwg = gridDim.x;
  const int bid = ((int)blockIdx.x % 8) * (nwg / 8) + (int)blockIdx.x / 8;
  const int t = threadIdx.x;
  const int lane = t & 63, wv = t >> 6;
  const int wr = wv >> 1, wc = wv & 1;
  const int tn = bid & 15;                      // 2048/128 = 16 N tiles
  const size_t m0 = (size_t)(bid >> 4) * BM;
  const int n0 = tn * BN;
  f32x4 acc[4][4] = {};
  const int fr = lane & 15;
  const int kq = (lane >> 4) * 8;

  for (int k0 = 0; k0 < H_DIM; k0 += BK) {
#pragma unroll
    for (int it = 0; it < 4; ++it) {
      const int idx = (it * 4 + wv) * 64 + lane;
      const int row = idx >> 3;
      const int c8 = (idx & 7) * 8;
      const size_t aoff = (m0 + row) * (size_t)H_DIM + k0 + c8;
      const size_t boff = (size_t)(n0 + row) * H_DIM + k0 + c8;
      __builtin_amdgcn_global_load_lds(
          (const __attribute__((address_space(1))) void*)(Ahi_g + aoff),
          (__attribute__((address_space(3))) void*)&As[0][row][c8], 16, 0, 0);
      __builtin_amdgcn_global_load_lds(
          (const __attribute__((address_space(1))) void*)(Alo_g + aoff),
          (__attribute__((address_space(3))) void*)&As[1][row][c8], 16, 0, 0);
      __builtin_amdgcn_global_load_lds(
          (const __attribute__((address_space(1))) void*)(Bhi_g + boff),
          (__attribute__((address_space(3))) void*)&Bs[0][row][c8], 16, 0, 0);
      __builtin_amdgcn_global_load_lds(
          (const __attribute__((address_space(1))) void*)(Blo_g + boff),
          (__attribute__((address_space(3))) void*)&Bs[1][row][c8], 16, 0, 0);
    }
    __syncthreads();
#pragma unroll
    for (int kk = 0; kk < 2; ++kk) {
      bfrag8 ah[4], al[4], bh[4], bl[4];
      const int kb = kk * 32 + kq;
#pragma unroll
      for (int mr = 0; mr < 4; ++mr) {
        ah[mr] = *(const bfrag8*)&As[0][wr * 64 + mr * 16 + fr][kb];
        al[mr] = *(const bfrag8*)&As[1][wr * 64 + mr * 16 + fr][kb];
      }
#pragma unroll
      for (int nr = 0; nr < 4; ++nr) {
        bh[nr] = *(const bfrag8*)&Bs[0][wc * 64 + nr * 16 + fr][kb];
        bl[nr] = *(const bfrag8*)&Bs[1][wc * 64 + nr * 16 + fr][kb];
      }
#pragma unroll
      for (int mr = 0; mr < 4; ++mr)
#pragma unroll
        for (int nr = 0; nr < 4; ++nr) {
          acc[mr][nr] = __builtin_amdgcn_mfma_f32_16x16x32_bf16(ah[mr], bh[nr], acc[mr][nr], 0, 0, 0);
          acc[mr][nr] = __builtin_amdgcn_mfma_f32_16x16x32_bf16(ah[mr], bl[nr], acc[mr][nr], 0, 0, 0);
          acc[mr][nr] = __builtin_amdgcn_mfma_f32_16x16x32_bf16(al[mr], bh[nr], acc[mr][nr], 0, 0, 0);
        }
    }
    __syncthreads();
  }
  const int rq = (lane >> 4) * 4;
#pragma unroll
  for (int nr = 0; nr < 4; ++nr) {
    const int col = n0 + wc * 64 + nr * 16 + fr;
    const float bv = bias[col];
#pragma unroll
    for (int mr = 0; mr < 4; ++mr) {
#pragma unroll
      for (int j = 0; j < 4; ++j) {
        const size_t row = m0 + wr * 64 + mr * 16 + rq + j;
        const size_t o = row * (size_t)L_DIM + col;
        float vv = acc[mr][nr][j] + bv;
        vv = vv >= 0.f ? vv : SLOPE_C * vv;
        OutZ[o] = OutZ[o] + vv;   // z (read) + h, in-place finalize
      }
    }
  }
}

// ---------------------------------------------------------------------------
// Launch
// ---------------------------------------------------------------------------
extern "C" void kernel_launch(void* const* d_in, const int* in_sizes, int n_in,
                              void* d_out, int out_size, void* d_ws, size_t ws_size,
                              hipStream_t stream) {
  const float* src    = (const float*)d_in[0];
  const float* tgt    = (const float*)d_in[1];
  const float* conv_w = (const float*)d_in[2];
  const float* conv_b = (const float*)d_in[3];
  const float* W1     = (const float*)d_in[4];
  const float* b1     = (const float*)d_in[5];
  const float* W2     = (const float*)d_in[6];
  const float* b2     = (const float*)d_in[7];
  float* out = (float*)d_out;

  char* ws = (char*)d_ws;
  // workspace layout (160 MB total)
  float* xn  = (float*)(ws);                                   // 16 MB
  u16* W1hi  = (u16*)(ws + ((size_t)16 << 20));                // 4 MB
  u16* W1lo  = (u16*)(ws + ((size_t)20 << 20));                // 4 MB
  u16* W2hi  = (u16*)(ws + ((size_t)24 << 20));                // 4 MB
  u16* W2lo  = (u16*)(ws + ((size_t)28 << 20));                // 4 MB
  u16* Hhi   = (u16*)(ws + ((size_t)32 << 20));                // 64 MB
  u16* Hlo   = (u16*)(ws + ((size_t)96 << 20));                // 64 MB

  norm_kernel<<<B_ROWS, 256, 0, stream>>>(src, tgt, xn);
  conv_kernel<<<dim3(L_DIM / 256, B_ROWS), 256, 0, stream>>>(xn, conv_w, conv_b, out);
  split_kernel<<<(H_DIM * L_DIM + 255) / 256, 256, 0, stream>>>(W1, W1hi, W1lo, H_DIM * L_DIM);
  split_kernel<<<(L_DIM * H_DIM + 255) / 256, 256, 0, stream>>>(W2, W2hi, W2lo, L_DIM * H_DIM);
  gemm1_kernel<<<(M_DIM / BM) * (H_DIM / BN), 256, 0, stream>>>(out, W1hi, W1lo, b1, Hhi, Hlo);
  gemm2_kernel<<<(M_DIM / BM) * (L_DIM / BN), 256, 0, stream>>>(Hhi, Hlo, W2hi, W2lo, b2, out);
}

// Round 2
// 1190.262 us; speedup vs baseline: 1.0497x; 1.0497x over previous
//
#include <hip/hip_runtime.h>
#include <hip/hip_bf16.h>
#include <cstdint>
#include <cstddef>

// Problem dims (fixed by the reference)
#define B_ROWS 2048
#define L_DIM  2048
#define NBR    16
#define H_DIM  1024
#define M_DIM  (B_ROWS * NBR)   // 32768
#define SLOPE_C 0.01f

#define BM 128
#define BN 128
#define BK 64

typedef unsigned short u16;
typedef __attribute__((ext_vector_type(4))) float f32x4;
typedef __attribute__((ext_vector_type(4))) short s16x4;
typedef __attribute__((ext_vector_type(8))) __bf16 bfrag8;   // MFMA operand (4 VGPRs)

// LDS tiles are [128 rows][64 u16] = 128B row pitch = exactly 32 banks ->
// un-swizzled ds_read_b128 is a same-bank pileup (measured 1.0e8 conflict
// cycles, 32% of gemm2 time).  Swizzle: 16B-chunk' = chunk ^ (row&7).
// global_load_lds writes linearly (wave base + lane*16), so the swizzle is
// realized by permuting the per-lane GLOBAL source chunk; reads XOR the same
// pattern.  Reg-staged writes (gemm1 A) XOR the ds_write column directly.

// ---------------------------------------------------------------------------
// Kernel 1: row-wise quicknorm of concat(src, tgt) -> xn (fp32)
// ---------------------------------------------------------------------------
__global__ __launch_bounds__(256) void norm_kernel(const float* __restrict__ src,
                                                   const float* __restrict__ tgt,
                                                   float* __restrict__ xn) {
  const int b = blockIdx.x;
  const int t = threadIdx.x;
  const float* srow = src + (size_t)b * (L_DIM - 4);
  const float* trow = tgt + (size_t)b * 4;
  float v[8];
  float s = 0.f, ss = 0.f;
#pragma unroll
  for (int i = 0; i < 8; ++i) {
    const int idx = t + i * 256;
    const float x = (idx < L_DIM - 4) ? srow[idx] : trow[idx - (L_DIM - 4)];
    v[i] = x;
    s += x;
    ss += x * x;
  }
#pragma unroll
  for (int o = 32; o > 0; o >>= 1) {
    s  += __shfl_xor(s, o, 64);
    ss += __shfl_xor(ss, o, 64);
  }
  __shared__ float red[2][4];
  const int lane = t & 63, wv = t >> 6;
  if (lane == 0) { red[0][wv] = s; red[1][wv] = ss; }
  __syncthreads();
  s  = red[0][0] + red[0][1] + red[0][2] + red[0][3];
  ss = red[1][0] + red[1][1] + red[1][2] + red[1][3];
  const float mu  = s * (1.f / L_DIM);
  const float var = (ss - (float)L_DIM * mu * mu) * (1.f / (L_DIM - 1));
  const float inv = 1.f / sqrtf(var);   // quicknorm: (x-mu)/sd, ddof=1
  float* xrow = xn + (size_t)b * L_DIM;
#pragma unroll
  for (int i = 0; i < 8; ++i) {
    const int idx = t + i * 256;
    xrow[idx] = (v[i] - mu) * inv;
  }
}

// ---------------------------------------------------------------------------
// Kernel 2: 16 reflect-padded conv branches -> z (fp32) stored in d_out
// ---------------------------------------------------------------------------
__global__ __launch_bounds__(256) void conv_kernel(const float* __restrict__ xn,
                                                   const float* __restrict__ conv_w,
                                                   const float* __restrict__ conv_b,
                                                   float* __restrict__ z) {
  __shared__ float win[272];
  __shared__ float cw[16][16];
  __shared__ float cb[16];
  const int b  = blockIdx.y;
  const int l0 = blockIdx.x * 256;
  const int t  = threadIdx.x;
  cw[t >> 4][t & 15] = conv_w[t];
  if (t < 16) cb[t] = conv_b[t];
  const float* xrow = xn + (size_t)b * L_DIM;
  for (int i = t; i < 271; i += 256) {
    int g = l0 - 7 + i;            // global position, range [-7, L+14]
    int r = g < 0 ? -g : g;        // jnp.pad 'reflect' (edge not repeated)
    if (r >= L_DIM) r = 2 * L_DIM - 2 - r;
    win[i] = xrow[r];
  }
  __syncthreads();
  const int l = l0 + t;
  float* zb = z + (size_t)b * NBR * L_DIM + l;
#pragma unroll
  for (int k = 0; k < NBR; ++k) {
    const int left = k >> 1;
    float a = cb[k];
    const int base = t + 7 - left;
#pragma unroll
    for (int j = 0; j <= k; ++j) a += cw[k][j] * win[base + j];
    zb[(size_t)k * L_DIM] = a;
  }
}

// ---------------------------------------------------------------------------
// Kernel 3: split fp32 -> (hi, lo) truncated bf16 pair.
// ---------------------------------------------------------------------------
__global__ __launch_bounds__(256) void split_kernel(const float* __restrict__ src,
                                                    u16* __restrict__ hi,
                                                    u16* __restrict__ lo, int n) {
  const int i = blockIdx.x * 256 + threadIdx.x;
  if (i >= n) return;
  const float f = src[i];
  const unsigned u = __float_as_uint(f);
  const u16 h = (u16)(u >> 16);
  const float r = f - __uint_as_float(u & 0xFFFF0000u);  // exact
  hi[i] = h;
  lo[i] = (u16)(__float_as_uint(r) >> 16);
}

// ---------------------------------------------------------------------------
// GEMM1: H = lrelu(Z @ W1^T + b1).  Z fp32 [32768][2048] (in d_out),
// W1 pre-split hi/lo bf16 [1024][2048].  Output H as hi/lo bf16 [32768][1024].
// 3-term split product: Ahi*Bhi + Ahi*Blo + Alo*Bhi.
// ---------------------------------------------------------------------------
__global__ __launch_bounds__(256, 2) void gemm1_kernel(
    const float* __restrict__ Z,
    const u16* __restrict__ Bhi_g, const u16* __restrict__ Blo_g,
    const float* __restrict__ bias,
    u16* __restrict__ Hhi, u16* __restrict__ Hlo) {
  __shared__ u16 As[2][BM][BK];   // [hi/lo][row][k]  2*16KB, XOR-swizzled cols
  __shared__ u16 Bs[2][BM][BK];   // 2*16KB, XOR-swizzled cols
  const int nwg = gridDim.x;
  const int bid = ((int)blockIdx.x % 8) * (nwg / 8) + (int)blockIdx.x / 8;  // XCD chunk
  const int t = threadIdx.x;
  const int lane = t & 63, wv = t >> 6;
  const int wr = wv >> 1, wc = wv & 1;
  const int tn = bid & 7;                       // 1024/128 = 8 N tiles
  const size_t m0 = (size_t)(bid >> 3) * BM;
  const int n0 = tn * BN;
  f32x4 acc[4][4] = {};
  const int a_c4 = (t & 15) * 4;                // elem col of this thread's 8B A chunk
  const int a_r0 = t >> 4;                      // base LDS row for A staging
  const int awc  = a_c4 ^ ((a_r0 & 7) << 3);    // swizzled A write col (row&7 inv. in i)
  const int fr = lane & 15;
  const int kq = (lane >> 4) * 8;
  const int sx = (fr & 7) << 3;                 // read-side XOR (row&7 == fr&7)

  for (int k0 = 0; k0 < L_DIM; k0 += BK) {
    // --- stage A: fp32 -> hi/lo bf16 in LDS (reg-staged, swizzled ds_write)
#pragma unroll
    for (int i = 0; i < 8; ++i) {
      const int row = a_r0 + i * 16;
      const f32x4 v = *(const f32x4*)(Z + (m0 + row) * (size_t)L_DIM + k0 + a_c4);
      s16x4 hi4, lo4;
#pragma unroll
      for (int e = 0; e < 4; ++e) {
        const unsigned u = __float_as_uint(v[e]);
        hi4[e] = (short)(u >> 16);
        const float r = v[e] - __uint_as_float(u & 0xFFFF0000u);
        lo4[e] = (short)(__float_as_uint(r) >> 16);
      }
      *(s16x4*)&As[0][row][awc] = hi4;
      *(s16x4*)&As[1][row][awc] = lo4;
    }
    // --- stage B: async global->LDS, width 16; swizzle via per-lane SOURCE chunk
#pragma unroll
    for (int it = 0; it < 4; ++it) {
      const int idx = (it * 4 + wv) * 64 + lane;
      const int row = idx >> 3;
      const int ch = idx & 7;                   // linear LDS chunk this lane fills
      const int sc = ch ^ (row & 7);            // global chunk that belongs there
      const size_t goff = (size_t)(n0 + row) * L_DIM + k0 + sc * 8;
      __builtin_amdgcn_global_load_lds(
          (const __attribute__((address_space(1))) void*)(Bhi_g + goff),
          (__attribute__((address_space(3))) void*)&Bs[0][row][ch * 8], 16, 0, 0);
      __builtin_amdgcn_global_load_lds(
          (const __attribute__((address_space(1))) void*)(Blo_g + goff),
          (__attribute__((address_space(3))) void*)&Bs[1][row][ch * 8], 16, 0, 0);
    }
    __syncthreads();
    // --- MFMA: 2 k-substeps x 4x4 fragments x 3 split terms
#pragma unroll
    for (int kk = 0; kk < 2; ++kk) {
      bfrag8 ah[4], al[4], bh[4], bl[4];
      const int kb = (kk * 32 + kq) ^ sx;       // swizzled read col
#pragma unroll
      for (int mr = 0; mr < 4; ++mr) {
        ah[mr] = *(const bfrag8*)&As[0][wr * 64 + mr * 16 + fr][kb];
        al[mr] = *(const bfrag8*)&As[1][wr * 64 + mr * 16 + fr][kb];
      }
#pragma unroll
      for (int nr = 0; nr < 4; ++nr) {
        bh[nr] = *(const bfrag8*)&Bs[0][wc * 64 + nr * 16 + fr][kb];
        bl[nr] = *(const bfrag8*)&Bs[1][wc * 64 + nr * 16 + fr][kb];
      }
#pragma unroll
      for (int mr = 0; mr < 4; ++mr)
#pragma unroll
        for (int nr = 0; nr < 4; ++nr) {
          acc[mr][nr] = __builtin_amdgcn_mfma_f32_16x16x32_bf16(ah[mr], bh[nr], acc[mr][nr], 0, 0, 0);
          acc[mr][nr] = __builtin_amdgcn_mfma_f32_16x16x32_bf16(ah[mr], bl[nr], acc[mr][nr], 0, 0, 0);
          acc[mr][nr] = __builtin_amdgcn_mfma_f32_16x16x32_bf16(al[mr], bh[nr], acc[mr][nr], 0, 0, 0);
        }
    }
    __syncthreads();
  }
  // --- epilogue: bias + leaky_relu, write h as hi/lo bf16
  const int rq = (lane >> 4) * 4;
#pragma unroll
  for (int nr = 0; nr < 4; ++nr) {
    const int col = n0 + wc * 64 + nr * 16 + fr;
    const float bv = bias[col];
#pragma unroll
    for (int mr = 0; mr < 4; ++mr) {
#pragma unroll
      for (int j = 0; j < 4; ++j) {
        const size_t row = m0 + wr * 64 + mr * 16 + rq + j;   // C/D: col=lane&15, row=(lane>>4)*4+j
        float vv = acc[mr][nr][j] + bv;
        vv = vv >= 0.f ? vv : SLOPE_C * vv;
        const unsigned u = __float_as_uint(vv);
        const float r = vv - __uint_as_float(u & 0xFFFF0000u);
        Hhi[row * H_DIM + col] = (u16)(u >> 16);
        Hlo[row * H_DIM + col] = (u16)(__float_as_uint(r) >> 16);
      }
    }
  }
}

// ---------------------------------------------------------------------------
// GEMM2: out = z + lrelu(H @ W2^T + b2).  H hi/lo bf16 [32768][1024],
// W2 hi/lo bf16 [2048][1024].  z fp32 lives in d_out; in-place finalize.
// ---------------------------------------------------------------------------
__global__ __launch_bounds__(256, 2) void gemm2_kernel(
    const u16* __restrict__ Ahi_g, const u16* __restrict__ Alo_g,
    const u16* __restrict__ Bhi_g, const u16* __restrict__ Blo_g,
    const float* __restrict__ bias,
    float* __restrict__ OutZ) {
  __shared__ u16 As[2][BM][BK];
  __shared__ u16 Bs[2][BM][BK];
  const int nwg = gridDim.x;
  const int bid = ((int)blockIdx.x % 8) * (nwg / 8) + (int)blockIdx.x / 8;
  const int t = threadIdx.x;
  const int lane = t & 63, wv = t >> 6;
  const int wr = wv >> 1, wc = wv & 1;
  const int tn = bid & 15;                      // 2048/128 = 16 N tiles
  const size_t m0 = (size_t)(bid >> 4) * BM;
  const int n0 = tn * BN;
  f32x4 acc[4][4] = {};
  const int fr = lane & 15;
  const int kq = (lane >> 4) * 8;
  const int sx = (fr & 7) << 3;

  for (int k0 = 0; k0 < H_DIM; k0 += BK) {
#pragma unroll
    for (int it = 0; it < 4; ++it) {
      const int idx = (it * 4 + wv) * 64 + lane;
      const int row = idx >> 3;
      const int ch = idx & 7;
      const int sc = ch ^ (row & 7);
      const size_t aoff = (m0 + row) * (size_t)H_DIM + k0 + sc * 8;
      const size_t boff = (size_t)(n0 + row) * H_DIM + k0 + sc * 8;
      __builtin_amdgcn_global_load_lds(
          (const __attribute__((address_space(1))) void*)(Ahi_g + aoff),
          (__attribute__((address_space(3))) void*)&As[0][row][ch * 8], 16, 0, 0);
      __builtin_amdgcn_global_load_lds(
          (const __attribute__((address_space(1))) void*)(Alo_g + aoff),
          (__attribute__((address_space(3))) void*)&As[1][row][ch * 8], 16, 0, 0);
      __builtin_amdgcn_global_load_lds(
          (const __attribute__((address_space(1))) void*)(Bhi_g + boff),
          (__attribute__((address_space(3))) void*)&Bs[0][row][ch * 8], 16, 0, 0);
      __builtin_amdgcn_global_load_lds(
          (const __attribute__((address_space(1))) void*)(Blo_g + boff),
          (__attribute__((address_space(3))) void*)&Bs[1][row][ch * 8], 16, 0, 0);
    }
    __syncthreads();
#pragma unroll
    for (int kk = 0; kk < 2; ++kk) {
      bfrag8 ah[4], al[4], bh[4], bl[4];
      const int kb = (kk * 32 + kq) ^ sx;
#pragma unroll
      for (int mr = 0; mr < 4; ++mr) {
        ah[mr] = *(const bfrag8*)&As[0][wr * 64 + mr * 16 + fr][kb];
        al[mr] = *(const bfrag8*)&As[1][wr * 64 + mr * 16 + fr][kb];
      }
#pragma unroll
      for (int nr = 0; nr < 4; ++nr) {
        bh[nr] = *(const bfrag8*)&Bs[0][wc * 64 + nr * 16 + fr][kb];
        bl[nr] = *(const bfrag8*)&Bs[1][wc * 64 + nr * 16 + fr][kb];
      }
#pragma unroll
      for (int mr = 0; mr < 4; ++mr)
#pragma unroll
        for (int nr = 0; nr < 4; ++nr) {
          acc[mr][nr] = __builtin_amdgcn_mfma_f32_16x16x32_bf16(ah[mr], bh[nr], acc[mr][nr], 0, 0, 0);
          acc[mr][nr] = __builtin_amdgcn_mfma_f32_16x16x32_bf16(ah[mr], bl[nr], acc[mr][nr], 0, 0, 0);
          acc[mr][nr] = __builtin_amdgcn_mfma_f32_16x16x32_bf16(al[mr], bh[nr], acc[mr][nr], 0, 0, 0);
        }
    }
    __syncthreads();
  }
  const int rq = (lane >> 4) * 4;
#pragma unroll
  for (int nr = 0; nr < 4; ++nr) {
    const int col = n0 + wc * 64 + nr * 16 + fr;
    const float bv = bias[col];
#pragma unroll
    for (int mr = 0; mr < 4; ++mr) {
#pragma unroll
      for (int j = 0; j < 4; ++j) {
        const size_t row = m0 + wr * 64 + mr * 16 + rq + j;
        const size_t o = row * (size_t)L_DIM + col;
        float vv = acc[mr][nr][j] + bv;
        vv = vv >= 0.f ? vv : SLOPE_C * vv;
        OutZ[o] = OutZ[o] + vv;   // z (read) + h, in-place finalize
      }
    }
  }
}

// ---------------------------------------------------------------------------
// Launch
// ---------------------------------------------------------------------------
extern "C" void kernel_launch(void* const* d_in, const int* in_sizes, int n_in,
                              void* d_out, int out_size, void* d_ws, size_t ws_size,
                              hipStream_t stream) {
  const float* src    = (const float*)d_in[0];
  const float* tgt    = (const float*)d_in[1];
  const float* conv_w = (const float*)d_in[2];
  const float* conv_b = (const float*)d_in[3];
  const float* W1     = (const float*)d_in[4];
  const float* b1     = (const float*)d_in[5];
  const float* W2     = (const float*)d_in[6];
  const float* b2     = (const float*)d_in[7];
  float* out = (float*)d_out;

  char* ws = (char*)d_ws;
  // workspace layout (160 MB total)
  float* xn  = (float*)(ws);                                   // 16 MB
  u16* W1hi  = (u16*)(ws + ((size_t)16 << 20));                // 4 MB
  u16* W1lo  = (u16*)(ws + ((size_t)20 << 20));                // 4 MB
  u16* W2hi  = (u16*)(ws + ((size_t)24 << 20));                // 4 MB
  u16* W2lo  = (u16*)(ws + ((size_t)28 << 20));                // 4 MB
  u16* Hhi   = (u16*)(ws + ((size_t)32 << 20));                // 64 MB
  u16* Hlo   = (u16*)(ws + ((size_t)96 << 20));                // 64 MB

  norm_kernel<<<B_ROWS, 256, 0, stream>>>(src, tgt, xn);
  conv_kernel<<<dim3(L_DIM / 256, B_ROWS), 256, 0, stream>>>(xn, conv_w, conv_b, out);
  split_kernel<<<(H_DIM * L_DIM + 255) / 256, 256, 0, stream>>>(W1, W1hi, W1lo, H_DIM * L_DIM);
  split_kernel<<<(L_DIM * H_DIM + 255) / 256, 256, 0, stream>>>(W2, W2hi, W2lo, L_DIM * H_DIM);
  gemm1_kernel<<<(M_DIM / BM) * (H_DIM / BN), 256, 0, stream>>>(out, W1hi, W1lo, b1, Hhi, Hlo);
  gemm2_kernel<<<(M_DIM / BM) * (L_DIM / BN), 256, 0, stream>>>(Hhi, Hlo, W2hi, W2lo, b2, out);
}